// Round 5
// baseline (162.596 us; speedup 1.0000x reference)
//
#include <hip/hip_runtime.h>

// Network_49873160241834: fused LIF scan (B=256,F=10,C=3,T=8192) + conv(c) + linear(f).
//
// Speculative time-chunking (32 chunks x 256 steps, 128-step v=0 warmup; LIF resets v
// to EXACTLY +0 on spike => warmup converges bit-exactly) + 2 chains/lane ILP.
// Grid (B, 8), 64 threads/block = 8 waves/CU; block cb owns chunks 4cb..4cb+3
// (half h lane: v0 -> chunk 4cb+2h, v1 -> chunk 4cb+2h+1).
//
// R5 change (R4 post-mortem: waves 90% stalled on address-divergent loads, ~20 cache
// lines per load inst serializing in the per-CU TA pipe): cooperative coalesced LDS
// staging. Per 32-step stage the wave loads all 40 streams (4 chunks x 10 f) x 32
// floats = 5 KB via 5 fully-coalesced dwordx4 loads, double-buffered in LDS with an
// XOR bank swizzle (conflict-free b128 writes). ds_write deferred after the stage's
// compute so global latency hides behind ~600 cyc of sim. Sim reads LDS b128.
//
// Spike capture: per step, __ballot -> wave-uniform 64-bit mask; lane (o,tt) latches
// all 4 chunk masks at step t==tt. Epilogue per 32-step window: 4 x 6 LDS-LUT lookups
// + 4 coalesced stores. EXACTNESS: v-update is separately-rounded f32 (no FMA);
// one flipped spike costs ~0.5 in the output.

#define T_LEN 8192
#define NF 10
#define NSEQ 30
#define CHUNK 256
#define WARM 128
#define NCHUNKS 32
#define CPB 4
#define GRIDY (NCHUNKS / CPB)   // 8
#define NSTAGE 12               // 4 warm + 8 main stages of 32 steps
#define FSTRIDE 36              // padded f-stride (words); 16B-aligned, swizzle-friendly
#define LDSW (CPB * NF * FSTRIDE)  // 1440 words per buffer

__device__ __forceinline__ float lif_step(float xx, float v, float k, float vt, bool& s) {
  float d  = __fsub_rn(xx, v);   // rounded f32 sub
  float p  = __fmul_rn(k, d);    // rounded f32 mul (NOT fused)
  float vn = __fadd_rn(v, p);    // rounded f32 add
  s = vn > vt;                   // == (fl(vn - vt) > 0) in IEEE f32
  return s ? 0.0f : vn;          // exact reset to +0
}

__device__ __forceinline__ float lut_sum(unsigned m, const float* lut, int o, float bias) {
  float acc = bias;
#pragma unroll
  for (int g = 0; g < 6; ++g) {
    unsigned val = (m >> (5 * g)) & 31u;
    acc += lut[(g * 2 + o) * 32 + val];
  }
  return acc;
}

__global__ __launch_bounds__(64, 2) void lif_chunked(
    const float* __restrict__ x,      // (B, F, T)
    const float* __restrict__ tau,    // (3)
    const float* __restrict__ vth,    // (3)
    const float* __restrict__ convw,  // (3)
    const float* __restrict__ convb,  // (1)
    const float* __restrict__ linw,   // (2,10)
    const float* __restrict__ linb,   // (2)
    float* __restrict__ out)          // (B, 2, T)
{
  const int b    = blockIdx.x;
  const int cb   = blockIdx.y;       // chunks 4cb .. 4cb+3
  const int lane = threadIdx.x;
  const int half = lane >> 5;
  const int j    = lane & 31;
  const bool active = j < NSEQ;
  const int c = active ? j / NF : 0;
  const int f = active ? j % NF : 0;
  const int fx = f & 7;              // read-side swizzle key

  __shared__ __align__(16) float xs[2 * LDSW];   // 11.52 KB staging, double-buffered
  __shared__ float lut[384];                     // conv+linear LUT, 1.5 KB

  // LUT[g][o][val] = sum over set bits p of val of convw[(5g+p)/10]*linw[o,(5g+p)%10]
#pragma unroll
  for (int e = 0; e < 6; ++e) {
    int id = lane + 64 * e;
    int g = id >> 6, rem = id & 63, oo = rem >> 5, val = rem & 31;
    float sacc = 0.0f;
#pragma unroll
    for (int p = 0; p < 5; ++p) {
      if (val & (1 << p)) {
        int jj = 5 * g + p;
        sacc += convw[jj / NF] * linw[oo * NF + (jj % NF)];
      }
    }
    lut[id] = sacc;
  }

  const float k  = __fmul_rn(0.001f, tau[c]);
  const float vt = active ? vth[c] : 3.0e38f;   // inactive lanes never spike
  const int cBase = cb * CPB;
  const int myc0  = cBase + 2 * half;           // this lane's v0-chunk

  // ---- cooperative loader precompute: 5 pieces per lane (320 = 40 streams x 8 x16B)
  const float* gbase[5];
  int ldsoff[5];   // word offset inside one buffer
  int Dl[5];       // t0 - ts per piece (128, or 0 for chunk 0's stream)
#pragma unroll
  for (int i = 0; i < 5; ++i) {
    int P = i * 64 + lane;
    int stream = P >> 3;          // 0..39
    int t16 = P & 7;              // 16B piece within 32-float stage block
    int q  = stream / NF;
    int fL = stream - q * NF;
    int t0q = (cBase + q) * CHUNK;
    int tsq = t0q - WARM; if (tsq < 0) tsq = 0;
    Dl[i] = t0q - tsq;
    gbase[i] = x + ((size_t)b * NF + fL) * (size_t)T_LEN + tsq + t16 * 4;
    ldsoff[i] = (q * NF + fL) * FSTRIDE + ((t16 ^ (fL & 7)) << 2);
  }

  // epilogue role: lane = (o, tt)
  const int o  = half;
  const int tt = j;
  float wsum = 0.0f;
#pragma unroll
  for (int f2 = 0; f2 < NF; ++f2) wsum += linw[o * NF + f2];
  const float bias = linb[o] + convb[0] * wsum;
  float* ob = out + ((size_t)b * 2 + o) * T_LEN + cBase * CHUNK + tt;

  // sim read bases (word offsets; qA = 2*half, qB = qA+1)
  const int rbA = (2 * half * NF + f) * FSTRIDE;
  const int rbB = rbA + NF * FSTRIDE;

  float v0 = 0.0f, v1 = 0.0f;

  // ---- stage 0: load + write + barrier (covers LUT init too)
  {
    float4 tmp[5];
#pragma unroll
    for (int i = 0; i < 5; ++i) tmp[i] = *(const float4*)(gbase[i]);
#pragma unroll
    for (int i = 0; i < 5; ++i) *(float4*)(xs + ldsoff[i]) = tmp[i];
  }
  __syncthreads();

  // ---- warm stages 0..3 (no spike capture)
#pragma unroll 1
  for (int s = 0; s < 4; ++s) {
    const int buf = s & 1;
    const int sn = s + 1;
    float4 tmp[5];
#pragma unroll
    for (int i = 0; i < 5; ++i) {
      int off = (sn < 4) ? sn * 32 : (Dl[i] + (sn - 4) * 32);
      tmp[i] = *(const float4*)(gbase[i] + off);
    }
    const float* baseA = xs + buf * LDSW + rbA;
    const float* baseB = xs + buf * LDSW + rbB;
#pragma unroll
    for (int g = 0; g < 8; ++g) {
      float4 qa = *(const float4*)(baseA + ((g ^ fx) << 2));
      float4 qb = *(const float4*)(baseB + ((g ^ fx) << 2));
      float xa[4] = {qa.x, qa.y, qa.z, qa.w};
      float xb[4] = {qb.x, qb.y, qb.z, qb.w};
#pragma unroll
      for (int r = 0; r < 4; ++r) {
        bool s0, s1;
        v0 = lif_step(xa[r], v0, k, vt, s0);
        v1 = lif_step(xb[r], v1, k, vt, s1);
      }
    }
    const int nb = sn & 1;
#pragma unroll
    for (int i = 0; i < 5; ++i) *(float4*)(xs + nb * LDSW + ldsoff[i]) = tmp[i];
    __syncthreads();
  }

  v0 = (myc0 == 0) ? 0.0f : v0;   // chunk 0's true initial state

  // ---- main stages 4..11: spike capture + fused conv+linear epilogue
#pragma unroll 1
  for (int s = 4; s < NSTAGE; ++s) {
    const int buf = s & 1;
    const bool pf = (s + 1 < NSTAGE);
    float4 tmp[5];
    if (pf) {
#pragma unroll
      for (int i = 0; i < 5; ++i) {
        int off = Dl[i] + (s + 1 - 4) * 32;
        tmp[i] = *(const float4*)(gbase[i] + off);
      }
    }
    const float* baseA = xs + buf * LDSW + rbA;
    const float* baseB = xs + buf * LDSW + rbB;
    unsigned m0 = 0, m1 = 0, m2 = 0, m3 = 0;
#pragma unroll
    for (int g = 0; g < 8; ++g) {
      float4 qa = *(const float4*)(baseA + ((g ^ fx) << 2));
      float4 qb = *(const float4*)(baseB + ((g ^ fx) << 2));
      float xa[4] = {qa.x, qa.y, qa.z, qa.w};
      float xb[4] = {qb.x, qb.y, qb.z, qb.w};
#pragma unroll
      for (int r = 0; r < 4; ++r) {
        bool s0, s1;
        v0 = lif_step(xa[r], v0, k, vt, s0);
        v1 = lif_step(xb[r], v1, k, vt, s1);
        unsigned long long ub0 = __ballot(s0);
        unsigned long long ub1 = __ballot(s1);
        const int t = g * 4 + r;  // compile-time after unroll
        if (tt == t) {
          m0 = (unsigned)(ub0 & 0xffffffffull);   // chunk cBase+0
          m1 = (unsigned)(ub1 & 0xffffffffull);   // chunk cBase+1
          m2 = (unsigned)(ub0 >> 32);             // chunk cBase+2
          m3 = (unsigned)(ub1 >> 32);             // chunk cBase+3
        }
      }
    }
    const int w = s - 4;
    ob[w * 32            ] = lut_sum(m0, lut, o, bias);
    ob[w * 32 + 1 * CHUNK] = lut_sum(m1, lut, o, bias);
    ob[w * 32 + 2 * CHUNK] = lut_sum(m2, lut, o, bias);
    ob[w * 32 + 3 * CHUNK] = lut_sum(m3, lut, o, bias);
    if (pf) {
      const int nb = (s + 1) & 1;
#pragma unroll
      for (int i = 0; i < 5; ++i) *(float4*)(xs + nb * LDSW + ldsoff[i]) = tmp[i];
    }
    __syncthreads();
  }
}

extern "C" void kernel_launch(void* const* d_in, const int* in_sizes, int n_in,
                              void* d_out, int out_size, void* d_ws, size_t ws_size,
                              hipStream_t stream) {
  const float* x     = (const float*)d_in[0];
  const float* tau   = (const float*)d_in[1];
  const float* vthp  = (const float*)d_in[2];
  const float* convw = (const float*)d_in[3];
  const float* convb = (const float*)d_in[4];
  const float* linw  = (const float*)d_in[5];
  const float* linb  = (const float*)d_in[6];
  float* out = (float*)d_out;

  const int B = in_sizes[0] / (NF * T_LEN);  // 256
  lif_chunked<<<dim3(B, GRIDY), dim3(64), 0, stream>>>(
      x, tau, vthp, convw, convb, linw, linb, out);
}